// Round 15
// baseline (312.118 us; speedup 1.0000x reference)
//
#include <hip/hip_runtime.h>
#include <hip/hip_bf16.h>

#define MINN 1e-15f
#define MAXN (1.0f - 4e-3f)
#define ATMAX 3.1063031f   // atanhf(1 - 4e-3)

#define NBH 9              // log2(nodes per bucket)
#define BNODES 512
#define BCAP 10240         // staging capacity per bucket
#define BWIN (BCAP + 4 * BNODES)
#define PBE 8192           // edges per pass-B block

typedef short short8 __attribute__((ext_vector_type(8)));
typedef float f32x4 __attribute__((ext_vector_type(4)));

__device__ __forceinline__ float wsum(float v) {
    v += __shfl_xor(v, 32, 64);
    v += __shfl_xor(v, 16, 64);
    v += __shfl_xor(v, 8, 64);
    v += __shfl_xor(v, 4, 64);
    v += __shfl_xor(v, 2, 64);
    v += __shfl_xor(v, 1, 64);
    return v;
}

// truncation split: f ~= bf16(hi) + bf16(lo), combined rel err ~2^-18
__device__ __forceinline__ void splitf(float f, short& hi, short& lo) {
    unsigned u = __float_as_uint(f);
    hi = (short)(u >> 16);
    float r = f - __uint_as_float(u & 0xffff0000u);
    lo = (short)(__float_as_uint(r) >> 16);
}

__device__ __forceinline__ unsigned packsplit_hi(short ha, short hb) {
    return (unsigned)(unsigned short)ha | ((unsigned)(unsigned short)hb << 16);
}

// RNE bf16 pack of two floats
__device__ __forceinline__ unsigned pack_bf16(float a, float b) {
    unsigned ua = __float_as_uint(a);
    unsigned ub = __float_as_uint(b);
    ua = (ua + 0x7fffu + ((ua >> 16) & 1u)) >> 16;
    ub = (ub + 0x7fffu + ((ub >> 16) & 1u)) & 0xffff0000u;
    return ua | ub;
}

// fast transcendentals (args >= 0 in all uses; err ~2e-7)
__device__ __forceinline__ float tanh_fast(float x) {
    float e = __expf(2.f * x);
    return (e - 1.f) * __builtin_amdgcn_rcpf(e + 1.f);
}
__device__ __forceinline__ float atanh_fast(float x) {
    return 0.5f * __logf((1.f + x) * __builtin_amdgcn_rcpf(1.f - x));
}

// cross-lane adds: xor1/xor2 via DPP quad_perm (VALU), xor4/xor8 via ds_swizzle.
// Control operands must be compile-time constants -> template parameters.
template <int CTRL>
__device__ __forceinline__ float qadd(float v) {
    return v + __int_as_float(__builtin_amdgcn_update_dpp(
        0, __float_as_int(v), CTRL, 0xF, 0xF, true));
}
#define DPP_XOR1 0xB1
#define DPP_XOR2 0x4E
template <int IMM>
__device__ __forceinline__ float swz_add(float v) {
    return v + __int_as_float(__builtin_amdgcn_ds_swizzle(__float_as_int(v), IMM));
}
#define SWZ_XOR4 0x101F
#define SWZ_XOR8 0x201F

// fragment index for A-side buffers: element (row, uint-col c)
__device__ __forceinline__ size_t fragidx(int row, int c) {
    return ((size_t)((row >> 4) * 4 + (c >> 4)) << 8) + ((((c >> 2) & 3) * 16 + (row & 15)) << 2) + (c & 3);
}

// ---------------- pass B: bin edges into 512-node buckets ----------------
__global__ __launch_bounds__(256) void k_bucket(const int* __restrict__ src, const int* __restrict__ dst,
                                                const float* __restrict__ ew, int* __restrict__ gcur,
                                                int2* __restrict__ staging, int E, int NBUCK) {
    __shared__ int hist[512];
    const int tid = threadIdx.x;
    const int e0 = blockIdx.x * PBE;
    for (int i = tid; i < 512; i += 256) hist[i] = 0;
    __syncthreads();
    #pragma unroll 4
    for (int j = 0; j < PBE / 256; j++) {
        int e = e0 + j * 256 + tid;
        if (e < E) atomicAdd(&hist[dst[e] >> NBH], 1);
    }
    __syncthreads();
    for (int b = tid; b < NBUCK; b += 256) {
        int c = hist[b];
        hist[b] = c ? atomicAdd(&gcur[b], c) : 0;
    }
    __syncthreads();
    #pragma unroll 4
    for (int j = 0; j < PBE / 256; j++) {
        int e = e0 + j * 256 + tid;
        if (e < E) {
            int d = dst[e];
            int bkt = d >> NBH;
            int pos = atomicAdd(&hist[bkt], 1);
            if (pos < BCAP)
                staging[(size_t)bkt * BCAP + pos] =
                    make_int2((src[e] & 0x1FFFF) | ((d & (BNODES - 1)) << 17), __float_as_int(ew[e]));
        }
    }
}

// ---------------- pass C: per-bucket CSR build ----------------
// Final csr.x holds PRESCALED src offset (src*64 uints) for the aggregation gather.
__global__ __launch_bounds__(256) void k_cbuild(const int* __restrict__ gcur, const int2* __restrict__ staging,
                                                int2* __restrict__ csr, int2* __restrict__ rp2, int N) {
    __shared__ int cnt[BNODES];
    __shared__ int base[BNODES];
    __shared__ int sbuf[256];
    const int tid = threadIdx.x;
    const int b = blockIdx.x;
    const int bcnt = min(gcur[b], BCAP);
    const int wbase = b * BWIN;
    const int2* st = staging + (size_t)b * BCAP;

    for (int i = tid; i < BNODES; i += 256) cnt[i] = 0;
    __syncthreads();
    for (int i = tid; i < bcnt; i += 256) {
        int nl = (st[i].x >> 17) & (BNODES - 1);
        atomicAdd(&cnt[nl], 1);
    }
    __syncthreads();
    int p0 = (cnt[2 * tid] + 3) & ~3;
    int p1 = (cnt[2 * tid + 1] + 3) & ~3;
    int s = p0 + p1;
    sbuf[tid] = s;
    __syncthreads();
    for (int off = 1; off < 256; off <<= 1) {
        int add = (tid >= off) ? sbuf[tid - off] : 0;
        __syncthreads();
        sbuf[tid] += add;
        __syncthreads();
    }
    int excl = sbuf[tid] - s;
    base[2 * tid] = excl;
    base[2 * tid + 1] = excl + p0;
    __syncthreads();
    for (int i = tid; i < BNODES; i += 256) {
        int node = b * BNODES + i;
        int c = cnt[i];
        int pd = (c + 3) & ~3;
        int gb = wbase + base[i];
        if (node < N) rp2[node] = make_int2(gb, pd);
        for (int k = c; k < pd; k++) csr[gb + k] = make_int2(0, 0);
    }
    __syncthreads();
    for (int i = tid; i < BNODES; i += 256) cnt[i] = wbase + base[i];
    __syncthreads();
    for (int i = tid; i < bcnt; i += 256) {
        int2 p = st[i];
        int nl = (p.x >> 17) & (BNODES - 1);
        int pos = atomicAdd(&cnt[nl], 1);
        csr[pos] = make_int2((p.x & 0x1FFFF) << 6, p.y);   // prescaled: src*64
    }
}

// ---------------- prep: split W into fragment-ordered bf16 hi/lo ----------------
__global__ __launch_bounds__(256) void k_wprep(const float* __restrict__ W1, const float* __restrict__ W2,
                                               unsigned* __restrict__ WH1, unsigned* __restrict__ WL1,
                                               unsigned* __restrict__ WH2, unsigned* __restrict__ WL2) {
    int f = (blockIdx.x & 31) * 256 + threadIdx.x;   // [0, 8192)
    const float* W = (blockIdx.x < 32) ? W1 : W2;
    unsigned* WH = (blockIdx.x < 32) ? WH1 : WH2;
    unsigned* WL = (blockIdx.x < 32) ? WL1 : WL2;
    int frag = f >> 8, rem = f & 255;
    int lane = rem >> 2, j = rem & 3;
    int lr = lane & 15, lg = lane >> 4;
    int wid = frag >> 3, ct = (frag >> 2) & 1, kt = frag & 3;
    int n = wid * 32 + 2 * lr + ct;
    int c = kt * 16 + lg * 4 + j;
    float a = W[n * 128 + 2 * c], b = W[n * 128 + 2 * c + 1];
    short ha, la, hb, lb;
    splitf(a, ha, la); splitf(b, hb, lb);
    WH[f] = packsplit_hi(ha, hb);
    WL[f] = packsplit_hi(la, lb);
}

// ---------------- prep: hyperbolic bias vectors ----------------
__global__ __launch_bounds__(64) void k_bias(const float* __restrict__ B1, const float* __restrict__ B2,
                                             float2* __restrict__ HB) {
    const int lane = threadIdx.x;
    const float* B = (blockIdx.x == 0) ? B1 : B2;
    float2 bb = *(const float2*)(B + 2 * lane);
    float nb2 = wsum(bb.x * bb.x + bb.y * bb.y);
    float nb = fmaxf(sqrtf(nb2), MINN);
    float tbc = fminf(tanh_fast(nb), MAXN);
    float fb = tbc / nb;
    HB[blockIdx.x * 65 + lane] = make_float2(fb * bb.x, fb * bb.y);
    if (lane == 0) HB[blockIdx.x * 65 + 64] = make_float2(tbc * tbc, 0.f);
}

// ---------------- prep: split x into fragment-ordered bf16 hi/lo + norms ----------------
__global__ __launch_bounds__(256) void k_encode(const float* __restrict__ X,
                                                unsigned* __restrict__ XH, unsigned* __restrict__ XL,
                                                float2* __restrict__ NRM, int N) {
    const int lane = threadIdx.x & 63;
    const int wid = threadIdx.x >> 6;
    int row = blockIdx.x * 4 + wid;
    if (row >= N) return;
    float2 u = *(const float2*)(X + (size_t)row * 128 + 2 * lane);
    float n2 = wsum(u.x * u.x + u.y * u.y);
    short h0, l0, h1, l1;
    splitf(u.x, h0, l0); splitf(u.y, h1, l1);
    size_t idx = fragidx(row, lane);
    XH[idx] = packsplit_hi(h0, h1);
    XL[idx] = packsplit_hi(l0, l1);
    if (lane == 0) {
        float n0 = fmaxf(sqrtf(n2), MINN);
        NRM[row] = make_float2(n0, fminf(n0, ATMAX));
    }
}

// ---------------- fused HypLinear: fragment loads, DPP/swizzle reduce, local chains ----------------
// Wave owns cols [wid*32, wid*32+32); tile ct covers interleaved cols wid*32+2*lr+ct.
// After the 16-lane reduce, each lane holds row sums for its lg-group's 4 rows ->
// computes its own 4 chain-coefficient pairs (no broadcast), stores directly.
__global__ __launch_bounds__(256) void k_linear(
    const unsigned* __restrict__ XHf, const unsigned* __restrict__ XLf,
    const unsigned* __restrict__ WHf, const unsigned* __restrict__ WLf,
    const float2* __restrict__ HB, const float2* __restrict__ NRM,
    unsigned* __restrict__ OUT, int N)
{
    __shared__ float pmn[4][4][4][4];   // [t][lg][wid][r]
    __shared__ float pdm[4][4][4][4];

    const int lane = threadIdx.x & 63;
    const int wid = threadIdx.x >> 6;
    const int lr = lane & 15;
    const int lg = lane >> 4;
    const int tbase = blockIdx.x * 4;
    const int ntiles = (N + 15) >> 4;

    // B fragments: contiguous 1KB loads
    short8 Bh[2][4], Bl[2][4];
    #pragma unroll
    for (int ct = 0; ct < 2; ct++) {
        #pragma unroll
        for (int kt = 0; kt < 4; kt++) {
            const int fb = ((wid * 2 + ct) * 4 + kt) << 8;
            Bh[ct][kt] = *(const short8*)(WHf + fb + lane * 4);
            Bl[ct][kt] = *(const short8*)(WLf + fb + lane * 4);
        }
    }
    const float2 hbc = HB[wid * 16 + lr];   // hb elems (2c, 2c+1) for c = wid*16+lr
    const float y2 = HB[64].x;

    f32x4 acc[4][2];

    #pragma unroll
    for (int t = 0; t < 4; t++) {
        const int tt = min(tbase + t, ntiles - 1);   // clamped (no break -> pipelining)

        short8 Ah[4], Al[4];
        #pragma unroll
        for (int kt = 0; kt < 4; kt++) {
            const int fa = (tt * 4 + kt) << 8;
            Ah[kt] = *(const short8*)(XHf + fa + lane * 4);
            Al[kt] = *(const short8*)(XLf + fa + lane * 4);
        }

        f32x4 a0 = {0.f, 0.f, 0.f, 0.f}, a1 = {0.f, 0.f, 0.f, 0.f};
        #pragma unroll
        for (int kt = 0; kt < 4; kt++) {
            a0 = __builtin_amdgcn_mfma_f32_16x16x32_bf16(Ah[kt], Bh[0][kt], a0, 0, 0, 0);
            a1 = __builtin_amdgcn_mfma_f32_16x16x32_bf16(Ah[kt], Bh[1][kt], a1, 0, 0, 0);
            a0 = __builtin_amdgcn_mfma_f32_16x16x32_bf16(Al[kt], Bh[0][kt], a0, 0, 0, 0);
            a1 = __builtin_amdgcn_mfma_f32_16x16x32_bf16(Al[kt], Bh[1][kt], a1, 0, 0, 0);
            a0 = __builtin_amdgcn_mfma_f32_16x16x32_bf16(Ah[kt], Bl[0][kt], a0, 0, 0, 0);
            a1 = __builtin_amdgcn_mfma_f32_16x16x32_bf16(Ah[kt], Bl[1][kt], a1, 0, 0, 0);
        }
        acc[t][0] = a0; acc[t][1] = a1;

        // per-row partials over this wave's 32 cols; C row = lg*4 + r
        float pm[4], pd[4];
        #pragma unroll
        for (int r = 0; r < 4; r++) {
            pm[r] = a0[r] * a0[r] + a1[r] * a1[r];
            pd[r] = a0[r] * hbc.x + a1[r] * hbc.y;
        }
        #pragma unroll
        for (int r = 0; r < 4; r++) { pm[r] = qadd<DPP_XOR1>(pm[r]); pd[r] = qadd<DPP_XOR1>(pd[r]); }
        #pragma unroll
        for (int r = 0; r < 4; r++) { pm[r] = qadd<DPP_XOR2>(pm[r]); pd[r] = qadd<DPP_XOR2>(pd[r]); }
        #pragma unroll
        for (int r = 0; r < 4; r++) { pm[r] = swz_add<SWZ_XOR4>(pm[r]); pd[r] = swz_add<SWZ_XOR4>(pd[r]); }
        #pragma unroll
        for (int r = 0; r < 4; r++) { pm[r] = swz_add<SWZ_XOR8>(pm[r]); pd[r] = swz_add<SWZ_XOR8>(pd[r]); }
        if (lr == 0) {
            *(float4*)&pmn[t][lg][wid][0] = make_float4(pm[0], pm[1], pm[2], pm[3]);
            *(float4*)&pdm[t][lg][wid][0] = make_float4(pd[0], pd[1], pd[2], pd[3]);
        }
    }
    __syncthreads();

    #pragma unroll
    for (int t = 0; t < 4; t++) {
        const int row0 = (tbase + t) << 4;

        // cross-wave sums for this lane's 4 rows (lg*4 + r)
        float4 m0_ = *(const float4*)pmn[t][lg][0];
        float4 m1_ = *(const float4*)pmn[t][lg][1];
        float4 m2_ = *(const float4*)pmn[t][lg][2];
        float4 m3_ = *(const float4*)pmn[t][lg][3];
        float4 d0_ = *(const float4*)pdm[t][lg][0];
        float4 d1_ = *(const float4*)pdm[t][lg][1];
        float4 d2_ = *(const float4*)pdm[t][lg][2];
        float4 d3_ = *(const float4*)pdm[t][lg][3];
        float mn2[4] = {(m0_.x + m1_.x) + (m2_.x + m3_.x), (m0_.y + m1_.y) + (m2_.y + m3_.y),
                        (m0_.z + m1_.z) + (m2_.z + m3_.z), (m0_.w + m1_.w) + (m2_.w + m3_.w)};
        float dmb[4] = {(d0_.x + d1_.x) + (d2_.x + d3_.x), (d0_.y + d1_.y) + (d2_.y + d3_.y),
                        (d0_.z + d1_.z) + (d2_.z + d3_.z), (d0_.w + d1_.w) + (d2_.w + d3_.w)};

        #pragma unroll
        for (int r = 0; r < 4; r++) {
            const int row = row0 + lg * 4 + r;
            float2 nr = NRM[min(row, N - 1)];
            float xn = fmaxf(nr.x, MINN);
            float axn = nr.y;
            float mxn = fmaxf(sqrtf(mn2[r]), MINN);
            float arg = (mxn / xn) * axn;
            float thc = fminf(tanh_fast(arg), MAXN);
            float f1 = thc / mxn;
            float x2 = thc * thc;
            float xy = f1 * dmb[r];
            float ca = 1.f + 2.f * xy + y2;
            float cb = 1.f - x2;
            float inv = 1.f / fmaxf(1.f + 2.f * xy + x2 * y2, MINN);
            float ng2 = inv * inv * (ca * ca * x2 + 2.f * ca * cb * xy + cb * cb * y2);
            float ng = fmaxf(sqrtf(ng2), MINN);
            float lf = atanh_fast(fminf(ng, MAXN)) / ng;
            float sle = lf * inv;
            float caf1 = sle * ca * f1;
            float cbs = sle * cb;
            if (row < N) {
                float o0 = caf1 * acc[t][0][r] + cbs * hbc.x;
                float o1 = caf1 * acc[t][1][r] + cbs * hbc.y;
                OUT[(size_t)row * 64 + wid * 16 + lr] = pack_bf16(o0, o1);
            }
        }
    }
}

// ---------------- fused aggregation + HypAct ----------------
// csr.x is prescaled (src*64): gather address = 1 v_add.
__global__ __launch_bounds__(256) void k_aggact(const unsigned* __restrict__ XT, const int2* __restrict__ rp2,
                                                const int2* __restrict__ csr,
                                                float* __restrict__ OUTF,
                                                unsigned* __restrict__ OUTH, unsigned* __restrict__ OUTL,
                                                float2* __restrict__ NRM, int N, int last) {
    const int lane = threadIdx.x & 63;
    const int wid = threadIdx.x >> 6;
    int node = blockIdx.x * 4 + wid;
    if (node >= N) return;
    int2 rr = rp2[node];
    int b = __builtin_amdgcn_readfirstlane(rr.x);
    int cnt = __builtin_amdgcn_readfirstlane(rr.y);
    int e8 = b + (cnt & ~7);

    float ax[8], ay[8];
    #pragma unroll
    for (int j = 0; j < 8; j++) { ax[j] = 0.f; ay[j] = 0.f; }

    for (int i = b; i < e8; i += 8) {
        int2 c[8];
        #pragma unroll
        for (int j = 0; j < 8; j++) c[j] = csr[i + j];
        unsigned v[8];
        #pragma unroll
        for (int j = 0; j < 8; j++) v[j] = XT[(unsigned)c[j].x + lane];
        #pragma unroll
        for (int j = 0; j < 8; j++) {
            float w = __int_as_float(c[j].y);
            ax[j] = fmaf(w, __uint_as_float(v[j] << 16), ax[j]);
            ay[j] = fmaf(w, __uint_as_float(v[j] & 0xffff0000u), ay[j]);
        }
    }
    if (cnt & 4) {
        int i = e8;
        int2 c[4];
        #pragma unroll
        for (int j = 0; j < 4; j++) c[j] = csr[i + j];
        unsigned v[4];
        #pragma unroll
        for (int j = 0; j < 4; j++) v[j] = XT[(unsigned)c[j].x + lane];
        #pragma unroll
        for (int j = 0; j < 4; j++) {
            float w = __int_as_float(c[j].y);
            ax[j] = fmaf(w, __uint_as_float(v[j] << 16), ax[j]);
            ay[j] = fmaf(w, __uint_as_float(v[j] & 0xffff0000u), ay[j]);
        }
    }
    float a0 = ((ax[0] + ax[1]) + (ax[2] + ax[3])) + ((ax[4] + ax[5]) + (ax[6] + ax[7]));
    float a1 = ((ay[0] + ay[1]) + (ay[2] + ay[3])) + ((ay[4] + ay[5]) + (ay[6] + ay[7]));

    // act: logmap0(proj(expmap0(agg))) = agg * min(n,ATMAX)/n
    float r0 = fmaxf(a0, 0.f), r1 = fmaxf(a1, 0.f);
    float n2 = a0 * a0 + a1 * a1;
    float q2 = r0 * r0 + r1 * r1;
    #pragma unroll
    for (int s = 32; s; s >>= 1) {
        n2 += __shfl_xor(n2, s, 64);
        q2 += __shfl_xor(q2, s, 64);
    }
    float n = fmaxf(sqrtf(n2), MINN);
    float cp = fminf(n, ATMAX) / n;
    float nq = fmaxf(cp * sqrtf(q2), MINN);
    float tq = fminf(tanh_fast(nq), MAXN);
    float f2 = tq / nq;
    float sc = f2 * cp;
    float o0 = sc * r0, o1 = sc * r1;
    if (last) {
        *(float2*)(OUTF + (size_t)node * 128 + 2 * lane) = make_float2(o0, o1);
    } else {
        short h0, l0, h1, l1;
        splitf(o0, h0, l0); splitf(o1, h1, l1);
        size_t idx = fragidx(node, lane);
        OUTH[idx] = packsplit_hi(h0, h1);
        OUTL[idx] = packsplit_hi(l0, l1);
        if (lane == 0) NRM[node] = make_float2(tq, fminf(nq, ATMAX));
    }
}

extern "C" void kernel_launch(void* const* d_in, const int* in_sizes, int n_in,
                              void* d_out, int out_size, void* d_ws, size_t ws_size,
                              hipStream_t stream) {
    const float* x  = (const float*)d_in[0];
    const float* W1 = (const float*)d_in[1];
    const float* b1 = (const float*)d_in[2];
    const float* W2 = (const float*)d_in[3];
    const float* b2 = (const float*)d_in[4];
    const float* ew = (const float*)d_in[5];
    const int* src  = (const int*)d_in[6];
    const int* dst  = (const int*)d_in[7];
    const int N = in_sizes[0] / 128;
    const int E = in_sizes[5];
    float* out = (float*)d_out;

    const int NBUCK = (N + BNODES - 1) >> NBH;
    const int EB = (E + PBE - 1) / PBE;
    const int ntiles = (N + 15) / 16;

    char* w = (char*)d_ws;
    unsigned* xt  = (unsigned*)w; w += (size_t)N * 64 * 4;          // bf16 tangent (linear->agg), row-major
    unsigned* xhf = (unsigned*)w; w += (size_t)ntiles * 1024 * 4;   // fragment-ordered hi
    unsigned* xlf = (unsigned*)w; w += (size_t)ntiles * 1024 * 4;   // fragment-ordered lo
    int2*   csr   = (int2*)w;   w += (size_t)NBUCK * BWIN * 8;
    float2* nrm   = (float2*)w; w += (size_t)N * 8;
    int2*   rp2   = (int2*)w;   w += (size_t)N * 8;
    int2*   staging = (int2*)w; w += (size_t)NBUCK * BCAP * 8;
    unsigned* wh1 = (unsigned*)w; w += 8192 * 4;
    unsigned* wl1 = (unsigned*)w; w += 8192 * 4;
    unsigned* wh2 = (unsigned*)w; w += 8192 * 4;
    unsigned* wl2 = (unsigned*)w; w += 8192 * 4;
    float2* hbuf  = (float2*)w; w += 2 * 65 * 8;
    int*    gcur  = (int*)w;    w += (size_t)NBUCK * 4 + 256;

    hipMemsetAsync(gcur, 0, (size_t)NBUCK * 4, stream);
    k_bucket<<<EB, 256, 0, stream>>>(src, dst, ew, gcur, staging, E, NBUCK);
    k_cbuild<<<NBUCK, 256, 0, stream>>>(gcur, staging, csr, rp2, N);
    k_wprep<<<64, 256, 0, stream>>>(W1, W2, wh1, wl1, wh2, wl2);
    k_bias<<<2, 64, 0, stream>>>(b1, b2, hbuf);

    const int rowblocks = (N + 3) / 4;
    const int nlb = (ntiles + 3) / 4;

    // encode: f32 x -> fragment-ordered hi/lo + norms
    k_encode<<<rowblocks, 256, 0, stream>>>(x, xhf, xlf, nrm, N);
    // layer 1
    k_linear<<<nlb, 256, 0, stream>>>(xhf, xlf, wh1, wl1, hbuf, nrm, xt, N);
    k_aggact<<<rowblocks, 256, 0, stream>>>(xt, rp2, csr, nullptr, xhf, xlf, nrm, N, 0);
    // layer 2 (fragment inputs + norms from aggact)
    k_linear<<<nlb, 256, 0, stream>>>(xhf, xlf, wh2, wl2, hbuf + 65, nrm, xt, N);
    k_aggact<<<rowblocks, 256, 0, stream>>>(xt, rp2, csr, out, nullptr, nullptr, nullptr, N, 1);
}

// Round 16
// 291.611 us; speedup vs baseline: 1.0703x; 1.0703x over previous
//
#include <hip/hip_runtime.h>
#include <hip/hip_bf16.h>
#include <hip/hip_fp16.h>

#define MINN 1e-15f
#define MAXN (1.0f - 4e-3f)
#define ATMAX 3.1063031f   // atanhf(1 - 4e-3)

#define NBH 9              // log2(nodes per bucket)
#define BNODES 512
#define BCAP 10240         // staging capacity per bucket
#define BWIN (BCAP + 4 * BNODES)
#define PBE 8192           // edges per pass-B block

typedef short short8 __attribute__((ext_vector_type(8)));
typedef float f32x4 __attribute__((ext_vector_type(4)));

__device__ __forceinline__ float wsum(float v) {
    v += __shfl_xor(v, 32, 64);
    v += __shfl_xor(v, 16, 64);
    v += __shfl_xor(v, 8, 64);
    v += __shfl_xor(v, 4, 64);
    v += __shfl_xor(v, 2, 64);
    v += __shfl_xor(v, 1, 64);
    return v;
}

// truncation split: f ~= bf16(hi) + bf16(lo), combined rel err ~2^-18
__device__ __forceinline__ void splitf(float f, short& hi, short& lo) {
    unsigned u = __float_as_uint(f);
    hi = (short)(u >> 16);
    float r = f - __uint_as_float(u & 0xffff0000u);
    lo = (short)(__float_as_uint(r) >> 16);
}

__device__ __forceinline__ unsigned packsplit_hi(short ha, short hb) {
    return (unsigned)(unsigned short)ha | ((unsigned)(unsigned short)hb << 16);
}

// RNE f16x2 pack (xt tangent buffer: |elem| <= ~3.11, f16-safe, more precise than bf16)
__device__ __forceinline__ unsigned pack_f16_rn(float a, float b) {
    __half2 h = __floats2half2_rn(a, b);
    return *(unsigned*)&h;
}

// packed-f16 dual FMA: lo_acc += f16lo(pk)*w ; hi_acc += f16hi(pk)*w  (one v_fma_mix each)
__device__ __forceinline__ void fma_mix2(float& lo_acc, float& hi_acc, unsigned pk, float w) {
    asm("v_fma_mix_f32 %0, %2, %3, %0 op_sel:[0,0,0] op_sel_hi:[1,0,0]\n\t"
        "v_fma_mix_f32 %1, %2, %3, %1 op_sel:[1,0,0] op_sel_hi:[1,0,0]"
        : "+v"(lo_acc), "+v"(hi_acc)
        : "v"(pk), "v"(w));
}

// fast transcendentals (args >= 0 in all uses; err ~2e-7)
__device__ __forceinline__ float tanh_fast(float x) {
    float e = __expf(2.f * x);
    return (e - 1.f) * __builtin_amdgcn_rcpf(e + 1.f);
}
__device__ __forceinline__ float atanh_fast(float x) {
    return 0.5f * __logf((1.f + x) * __builtin_amdgcn_rcpf(1.f - x));
}

// fragment index for A-side buffers: element (row, uint-col c)
__device__ __forceinline__ size_t fragidx(int row, int c) {
    return ((size_t)((row >> 4) * 4 + (c >> 4)) << 8) + ((((c >> 2) & 3) * 16 + (row & 15)) << 2) + (c & 3);
}

// ---------------- pass B: bin edges into 512-node buckets ----------------
__global__ __launch_bounds__(256) void k_bucket(const int* __restrict__ src, const int* __restrict__ dst,
                                                const float* __restrict__ ew, int* __restrict__ gcur,
                                                int2* __restrict__ staging, int E, int NBUCK) {
    __shared__ int hist[512];
    const int tid = threadIdx.x;
    const int e0 = blockIdx.x * PBE;
    for (int i = tid; i < 512; i += 256) hist[i] = 0;
    __syncthreads();
    #pragma unroll 4
    for (int j = 0; j < PBE / 256; j++) {
        int e = e0 + j * 256 + tid;
        if (e < E) atomicAdd(&hist[dst[e] >> NBH], 1);
    }
    __syncthreads();
    for (int b = tid; b < NBUCK; b += 256) {
        int c = hist[b];
        hist[b] = c ? atomicAdd(&gcur[b], c) : 0;
    }
    __syncthreads();
    #pragma unroll 4
    for (int j = 0; j < PBE / 256; j++) {
        int e = e0 + j * 256 + tid;
        if (e < E) {
            int d = dst[e];
            int bkt = d >> NBH;
            int pos = atomicAdd(&hist[bkt], 1);
            if (pos < BCAP)
                staging[(size_t)bkt * BCAP + pos] =
                    make_int2((src[e] & 0x1FFFF) | ((d & (BNODES - 1)) << 17), __float_as_int(ew[e]));
        }
    }
}

// ---------------- pass C: per-bucket CSR build ----------------
// Final csr.x holds PRESCALED src offset (src*64 uints) for the aggregation gather.
__global__ __launch_bounds__(256) void k_cbuild(const int* __restrict__ gcur, const int2* __restrict__ staging,
                                                int2* __restrict__ csr, int2* __restrict__ rp2, int N) {
    __shared__ int cnt[BNODES];
    __shared__ int base[BNODES];
    __shared__ int sbuf[256];
    const int tid = threadIdx.x;
    const int b = blockIdx.x;
    const int bcnt = min(gcur[b], BCAP);
    const int wbase = b * BWIN;
    const int2* st = staging + (size_t)b * BCAP;

    for (int i = tid; i < BNODES; i += 256) cnt[i] = 0;
    __syncthreads();
    for (int i = tid; i < bcnt; i += 256) {
        int nl = (st[i].x >> 17) & (BNODES - 1);
        atomicAdd(&cnt[nl], 1);
    }
    __syncthreads();
    int p0 = (cnt[2 * tid] + 3) & ~3;
    int p1 = (cnt[2 * tid + 1] + 3) & ~3;
    int s = p0 + p1;
    sbuf[tid] = s;
    __syncthreads();
    for (int off = 1; off < 256; off <<= 1) {
        int add = (tid >= off) ? sbuf[tid - off] : 0;
        __syncthreads();
        sbuf[tid] += add;
        __syncthreads();
    }
    int excl = sbuf[tid] - s;
    base[2 * tid] = excl;
    base[2 * tid + 1] = excl + p0;
    __syncthreads();
    for (int i = tid; i < BNODES; i += 256) {
        int node = b * BNODES + i;
        int c = cnt[i];
        int pd = (c + 3) & ~3;
        int gb = wbase + base[i];
        if (node < N) rp2[node] = make_int2(gb, pd);
        for (int k = c; k < pd; k++) csr[gb + k] = make_int2(0, 0);
    }
    __syncthreads();
    for (int i = tid; i < BNODES; i += 256) cnt[i] = wbase + base[i];
    __syncthreads();
    for (int i = tid; i < bcnt; i += 256) {
        int2 p = st[i];
        int nl = (p.x >> 17) & (BNODES - 1);
        int pos = atomicAdd(&cnt[nl], 1);
        csr[pos] = make_int2((p.x & 0x1FFFF) << 6, p.y);   // prescaled: src*64
    }
}

// ---------------- prep: split W into fragment-ordered bf16 hi/lo ----------------
__global__ __launch_bounds__(256) void k_wprep(const float* __restrict__ W1, const float* __restrict__ W2,
                                               unsigned* __restrict__ WH1, unsigned* __restrict__ WL1,
                                               unsigned* __restrict__ WH2, unsigned* __restrict__ WL2) {
    int f = (blockIdx.x & 31) * 256 + threadIdx.x;   // [0, 8192)
    const float* W = (blockIdx.x < 32) ? W1 : W2;
    unsigned* WH = (blockIdx.x < 32) ? WH1 : WH2;
    unsigned* WL = (blockIdx.x < 32) ? WL1 : WL2;
    int frag = f >> 8, rem = f & 255;
    int lane = rem >> 2, j = rem & 3;
    int lr = lane & 15, lg = lane >> 4;
    int wid = frag >> 3, ct = (frag >> 2) & 1, kt = frag & 3;
    int n = wid * 32 + 2 * lr + ct;
    int c = kt * 16 + lg * 4 + j;
    float a = W[n * 128 + 2 * c], b = W[n * 128 + 2 * c + 1];
    short ha, la, hb, lb;
    splitf(a, ha, la); splitf(b, hb, lb);
    WH[f] = packsplit_hi(ha, hb);
    WL[f] = packsplit_hi(la, lb);
}

// ---------------- prep: hyperbolic bias vectors ----------------
__global__ __launch_bounds__(64) void k_bias(const float* __restrict__ B1, const float* __restrict__ B2,
                                             float2* __restrict__ HB) {
    const int lane = threadIdx.x;
    const float* B = (blockIdx.x == 0) ? B1 : B2;
    float2 bb = *(const float2*)(B + 2 * lane);
    float nb2 = wsum(bb.x * bb.x + bb.y * bb.y);
    float nb = fmaxf(sqrtf(nb2), MINN);
    float tbc = fminf(tanh_fast(nb), MAXN);
    float fb = tbc / nb;
    HB[blockIdx.x * 65 + lane] = make_float2(fb * bb.x, fb * bb.y);
    if (lane == 0) HB[blockIdx.x * 65 + 64] = make_float2(tbc * tbc, 0.f);
}

// ---------------- prep: split x into fragment-ordered bf16 hi/lo + norms ----------------
__global__ __launch_bounds__(256) void k_encode(const float* __restrict__ X,
                                                unsigned* __restrict__ XH, unsigned* __restrict__ XL,
                                                float2* __restrict__ NRM, int N) {
    const int lane = threadIdx.x & 63;
    const int wid = threadIdx.x >> 6;
    int row = blockIdx.x * 4 + wid;
    if (row >= N) return;
    float2 u = *(const float2*)(X + (size_t)row * 128 + 2 * lane);
    float n2 = wsum(u.x * u.x + u.y * u.y);
    short h0, l0, h1, l1;
    splitf(u.x, h0, l0); splitf(u.y, h1, l1);
    size_t idx = fragidx(row, lane);
    XH[idx] = packsplit_hi(h0, h1);
    XL[idx] = packsplit_hi(l0, l1);
    if (lane == 0) {
        float n0 = fmaxf(sqrtf(n2), MINN);
        NRM[row] = make_float2(n0, fminf(n0, ATMAX));
    }
}

// ---------------- fused HypLinear: fragment loads + direct-store epilogue (round-13 form) ----------------
// Wave owns cols [wid*32, wid*32+32); tile ct covers interleaved cols wid*32+2*lr+ct,
// so a lane's (acc0[r], acc1[r]) is the adjacent pair (2c, 2c+1) -> direct f16 pack+store.
__global__ __launch_bounds__(256) void k_linear(
    const unsigned* __restrict__ XHf, const unsigned* __restrict__ XLf,
    const unsigned* __restrict__ WHf, const unsigned* __restrict__ WLf,
    const float2* __restrict__ HB, const float2* __restrict__ NRM,
    unsigned* __restrict__ OUT, int N)
{
    __shared__ float pmn[4][16][4];
    __shared__ float pdm[4][16][4];

    const int lane = threadIdx.x & 63;
    const int wid = threadIdx.x >> 6;
    const int lr = lane & 15;
    const int lg = lane >> 4;
    const int tbase = blockIdx.x * 4;

    // B fragments: contiguous 1KB loads
    short8 Bh[2][4], Bl[2][4];
    #pragma unroll
    for (int ct = 0; ct < 2; ct++) {
        #pragma unroll
        for (int kt = 0; kt < 4; kt++) {
            const int fb = ((wid * 2 + ct) * 4 + kt) << 8;
            Bh[ct][kt] = *(const short8*)(WHf + fb + lane * 4);
            Bl[ct][kt] = *(const short8*)(WLf + fb + lane * 4);
        }
    }
    const float2 hbc = HB[wid * 16 + lr];   // hb elems (2c, 2c+1) for c = wid*16+lr
    const float y2 = HB[64].x;

    f32x4 acc[4][2];

    #pragma unroll
    for (int t = 0; t < 4; t++) {
        const int row0 = (tbase + t) << 4;
        if (row0 >= N) break;

        short8 Ah[4], Al[4];
        #pragma unroll
        for (int kt = 0; kt < 4; kt++) {
            const int fa = ((tbase + t) * 4 + kt) << 8;
            Ah[kt] = *(const short8*)(XHf + fa + lane * 4);
            Al[kt] = *(const short8*)(XLf + fa + lane * 4);
        }

        f32x4 a0 = {0.f, 0.f, 0.f, 0.f}, a1 = {0.f, 0.f, 0.f, 0.f};
        #pragma unroll
        for (int kt = 0; kt < 4; kt++) {
            a0 = __builtin_amdgcn_mfma_f32_16x16x32_bf16(Ah[kt], Bh[0][kt], a0, 0, 0, 0);
            a1 = __builtin_amdgcn_mfma_f32_16x16x32_bf16(Ah[kt], Bh[1][kt], a1, 0, 0, 0);
            a0 = __builtin_amdgcn_mfma_f32_16x16x32_bf16(Al[kt], Bh[0][kt], a0, 0, 0, 0);
            a1 = __builtin_amdgcn_mfma_f32_16x16x32_bf16(Al[kt], Bh[1][kt], a1, 0, 0, 0);
            a0 = __builtin_amdgcn_mfma_f32_16x16x32_bf16(Ah[kt], Bl[0][kt], a0, 0, 0, 0);
            a1 = __builtin_amdgcn_mfma_f32_16x16x32_bf16(Ah[kt], Bl[1][kt], a1, 0, 0, 0);
        }
        acc[t][0] = a0; acc[t][1] = a1;

        // per-row partials over this wave's 32 cols; C row = lg*4 + r
        float pm[4], pd[4];
        #pragma unroll
        for (int r = 0; r < 4; r++) {
            pm[r] = a0[r] * a0[r] + a1[r] * a1[r];
            pd[r] = a0[r] * hbc.x + a1[r] * hbc.y;
        }
        #pragma unroll
        for (int s = 1; s <= 8; s <<= 1) {
            #pragma unroll
            for (int r = 0; r < 4; r++) {
                pm[r] += __shfl_xor(pm[r], s, 64);
                pd[r] += __shfl_xor(pd[r], s, 64);
            }
        }
        if (lr == 0) {
            #pragma unroll
            for (int r = 0; r < 4; r++) {
                pmn[t][lg * 4 + r][wid] = pm[r];
                pdm[t][lg * 4 + r][wid] = pd[r];
            }
        }
    }
    __syncthreads();

    #pragma unroll
    for (int t = 0; t < 4; t++) {
        const int row0 = (tbase + t) << 4;
        if (row0 >= N) break;

        // chain for row row0+lr (computed redundantly by the 4 lg groups)
        float4 qm = *(const float4*)pmn[t][lr];
        float4 qd = *(const float4*)pdm[t][lr];
        float mn2 = (qm.x + qm.y) + (qm.z + qm.w);
        float dmb = (qd.x + qd.y) + (qd.z + qd.w);
        const int crow = row0 + lr;
        float caf1 = 0.f, cbs = 0.f;
        if (crow < N) {
            float2 nr = NRM[crow];
            float xn = fmaxf(nr.x, MINN);
            float axn = nr.y;
            float mxn = fmaxf(sqrtf(mn2), MINN);
            float arg = (mxn / xn) * axn;
            float thc = fminf(tanh_fast(arg), MAXN);
            float f1 = thc / mxn;
            float x2 = thc * thc;
            float xy = f1 * dmb;
            float ca = 1.f + 2.f * xy + y2;
            float cb = 1.f - x2;
            float inv = 1.f / fmaxf(1.f + 2.f * xy + x2 * y2, MINN);
            float ng2 = inv * inv * (ca * ca * x2 + 2.f * ca * cb * xy + cb * cb * y2);
            float ng = fmaxf(sqrtf(ng2), MINN);
            float lf = atanh_fast(fminf(ng, MAXN)) / ng;
            float sle = lf * inv;
            caf1 = sle * ca * f1;
            cbs = sle * cb;
        }
        #pragma unroll
        for (int r = 0; r < 4; r++) {
            const int q = lg * 4 + r;
            float c1 = __shfl(caf1, q, 16);
            float c2 = __shfl(cbs, q, 16);
            const int row = row0 + q;
            if (row < N) {
                float o0 = c1 * acc[t][0][r] + c2 * hbc.x;
                float o1 = c1 * acc[t][1][r] + c2 * hbc.y;
                OUT[(size_t)row * 64 + wid * 16 + lr] = pack_f16_rn(o0, o1);
            }
        }
    }
}

// ---------------- fused aggregation + HypAct ----------------
// XT is f16-packed; csr.x prescaled (src*64). Unpack+FMA fused via v_fma_mix_f32.
__global__ __launch_bounds__(256) void k_aggact(const unsigned* __restrict__ XT, const int2* __restrict__ rp2,
                                                const int2* __restrict__ csr,
                                                float* __restrict__ OUTF,
                                                unsigned* __restrict__ OUTH, unsigned* __restrict__ OUTL,
                                                float2* __restrict__ NRM, int N, int last) {
    const int lane = threadIdx.x & 63;
    const int wid = threadIdx.x >> 6;
    int node = blockIdx.x * 4 + wid;
    if (node >= N) return;
    int2 rr = rp2[node];
    int b = __builtin_amdgcn_readfirstlane(rr.x);
    int cnt = __builtin_amdgcn_readfirstlane(rr.y);
    int e8 = b + (cnt & ~7);

    float ax[8], ay[8];
    #pragma unroll
    for (int j = 0; j < 8; j++) { ax[j] = 0.f; ay[j] = 0.f; }

    for (int i = b; i < e8; i += 8) {
        int2 c[8];
        #pragma unroll
        for (int j = 0; j < 8; j++) c[j] = csr[i + j];
        unsigned v[8];
        #pragma unroll
        for (int j = 0; j < 8; j++) v[j] = XT[(unsigned)c[j].x + lane];
        #pragma unroll
        for (int j = 0; j < 8; j++)
            fma_mix2(ax[j], ay[j], v[j], __int_as_float(c[j].y));
    }
    if (cnt & 4) {
        int i = e8;
        int2 c[4];
        #pragma unroll
        for (int j = 0; j < 4; j++) c[j] = csr[i + j];
        unsigned v[4];
        #pragma unroll
        for (int j = 0; j < 4; j++) v[j] = XT[(unsigned)c[j].x + lane];
        #pragma unroll
        for (int j = 0; j < 4; j++)
            fma_mix2(ax[j], ay[j], v[j], __int_as_float(c[j].y));
    }
    float a0 = ((ax[0] + ax[1]) + (ax[2] + ax[3])) + ((ax[4] + ax[5]) + (ax[6] + ax[7]));
    float a1 = ((ay[0] + ay[1]) + (ay[2] + ay[3])) + ((ay[4] + ay[5]) + (ay[6] + ay[7]));

    // act: logmap0(proj(expmap0(agg))) = agg * min(n,ATMAX)/n
    float r0 = fmaxf(a0, 0.f), r1 = fmaxf(a1, 0.f);
    float n2 = a0 * a0 + a1 * a1;
    float q2 = r0 * r0 + r1 * r1;
    #pragma unroll
    for (int s = 32; s; s >>= 1) {
        n2 += __shfl_xor(n2, s, 64);
        q2 += __shfl_xor(q2, s, 64);
    }
    float n = fmaxf(sqrtf(n2), MINN);
    float cp = fminf(n, ATMAX) / n;
    float nq = fmaxf(cp * sqrtf(q2), MINN);
    float tq = fminf(tanh_fast(nq), MAXN);
    float f2 = tq / nq;
    float sc = f2 * cp;
    float o0 = sc * r0, o1 = sc * r1;
    if (last) {
        *(float2*)(OUTF + (size_t)node * 128 + 2 * lane) = make_float2(o0, o1);
    } else {
        short h0, l0, h1, l1;
        splitf(o0, h0, l0); splitf(o1, h1, l1);
        size_t idx = fragidx(node, lane);
        OUTH[idx] = packsplit_hi(h0, h1);
        OUTL[idx] = packsplit_hi(l0, l1);
        if (lane == 0) NRM[node] = make_float2(tq, fminf(nq, ATMAX));
    }
}

extern "C" void kernel_launch(void* const* d_in, const int* in_sizes, int n_in,
                              void* d_out, int out_size, void* d_ws, size_t ws_size,
                              hipStream_t stream) {
    const float* x  = (const float*)d_in[0];
    const float* W1 = (const float*)d_in[1];
    const float* b1 = (const float*)d_in[2];
    const float* W2 = (const float*)d_in[3];
    const float* b2 = (const float*)d_in[4];
    const float* ew = (const float*)d_in[5];
    const int* src  = (const int*)d_in[6];
    const int* dst  = (const int*)d_in[7];
    const int N = in_sizes[0] / 128;
    const int E = in_sizes[5];
    float* out = (float*)d_out;

    const int NBUCK = (N + BNODES - 1) >> NBH;
    const int EB = (E + PBE - 1) / PBE;
    const int ntiles = (N + 15) / 16;

    char* w = (char*)d_ws;
    unsigned* xt  = (unsigned*)w; w += (size_t)N * 64 * 4;          // f16 tangent (linear->agg), row-major
    unsigned* xhf = (unsigned*)w; w += (size_t)ntiles * 1024 * 4;   // fragment-ordered hi
    unsigned* xlf = (unsigned*)w; w += (size_t)ntiles * 1024 * 4;   // fragment-ordered lo
    int2*   csr   = (int2*)w;   w += (size_t)NBUCK * BWIN * 8;
    float2* nrm   = (float2*)w; w += (size_t)N * 8;
    int2*   rp2   = (int2*)w;   w += (size_t)N * 8;
    int2*   staging = (int2*)w; w += (size_t)NBUCK * BCAP * 8;
    unsigned* wh1 = (unsigned*)w; w += 8192 * 4;
    unsigned* wl1 = (unsigned*)w; w += 8192 * 4;
    unsigned* wh2 = (unsigned*)w; w += 8192 * 4;
    unsigned* wl2 = (unsigned*)w; w += 8192 * 4;
    float2* hbuf  = (float2*)w; w += 2 * 65 * 8;
    int*    gcur  = (int*)w;    w += (size_t)NBUCK * 4 + 256;

    hipMemsetAsync(gcur, 0, (size_t)NBUCK * 4, stream);
    k_bucket<<<EB, 256, 0, stream>>>(src, dst, ew, gcur, staging, E, NBUCK);
    k_cbuild<<<NBUCK, 256, 0, stream>>>(gcur, staging, csr, rp2, N);
    k_wprep<<<64, 256, 0, stream>>>(W1, W2, wh1, wl1, wh2, wl2);
    k_bias<<<2, 64, 0, stream>>>(b1, b2, hbuf);

    const int rowblocks = (N + 3) / 4;
    const int nlb = (ntiles + 3) / 4;

    // encode: f32 x -> fragment-ordered hi/lo + norms
    k_encode<<<rowblocks, 256, 0, stream>>>(x, xhf, xlf, nrm, N);
    // layer 1
    k_linear<<<nlb, 256, 0, stream>>>(xhf, xlf, wh1, wl1, hbuf, nrm, xt, N);
    k_aggact<<<rowblocks, 256, 0, stream>>>(xt, rp2, csr, nullptr, xhf, xlf, nrm, N, 0);
    // layer 2 (fragment inputs + norms from aggact)
    k_linear<<<nlb, 256, 0, stream>>>(xhf, xlf, wh2, wl2, hbuf + 65, nrm, xt, N);
    k_aggact<<<rowblocks, 256, 0, stream>>>(xt, rp2, csr, out, nullptr, nullptr, nullptr, N, 1);
}

// Round 18
// 285.708 us; speedup vs baseline: 1.0924x; 1.0207x over previous
//
#include <hip/hip_runtime.h>
#include <hip/hip_bf16.h>
#include <hip/hip_fp16.h>

#define MINN 1e-15f
#define MAXN (1.0f - 4e-3f)
#define ATMAX 3.1063031f   // atanhf(1 - 4e-3)

#define NBH 9              // log2(nodes per bucket)
#define BNODES 512
#define BCAP 10240         // staging capacity per bucket
#define BWIN (BCAP + 4 * BNODES)
#define PBE 8192           // edges per pass-B block

typedef short short8 __attribute__((ext_vector_type(8)));
typedef float f32x4 __attribute__((ext_vector_type(4)));

__device__ __forceinline__ float wsum(float v) {
    v += __shfl_xor(v, 32, 64);
    v += __shfl_xor(v, 16, 64);
    v += __shfl_xor(v, 8, 64);
    v += __shfl_xor(v, 4, 64);
    v += __shfl_xor(v, 2, 64);
    v += __shfl_xor(v, 1, 64);
    return v;
}

// truncation split: f ~= bf16(hi) + bf16(lo), combined rel err ~2^-18
__device__ __forceinline__ void splitf(float f, short& hi, short& lo) {
    unsigned u = __float_as_uint(f);
    hi = (short)(u >> 16);
    float r = f - __uint_as_float(u & 0xffff0000u);
    lo = (short)(__float_as_uint(r) >> 16);
}

__device__ __forceinline__ unsigned packsplit_hi(short ha, short hb) {
    return (unsigned)(unsigned short)ha | ((unsigned)(unsigned short)hb << 16);
}

// RNE f16x2 pack (xt tangent buffer: |elem| <= ~3.11, f16-safe, more precise than bf16)
__device__ __forceinline__ unsigned pack_f16_rn(float a, float b) {
    __half2 h = __floats2half2_rn(a, b);
    return *(unsigned*)&h;
}

// packed-f16 dual FMA: lo_acc += f16lo(pk)*w ; hi_acc += f16hi(pk)*w  (one v_fma_mix each)
__device__ __forceinline__ void fma_mix2(float& lo_acc, float& hi_acc, unsigned pk, float w) {
    asm("v_fma_mix_f32 %0, %2, %3, %0 op_sel:[0,0,0] op_sel_hi:[1,0,0]\n\t"
        "v_fma_mix_f32 %1, %2, %3, %1 op_sel:[1,0,0] op_sel_hi:[1,0,0]"
        : "+v"(lo_acc), "+v"(hi_acc)
        : "v"(pk), "v"(w));
}

// fast transcendentals (args >= 0 in all uses; err ~2e-7)
__device__ __forceinline__ float tanh_fast(float x) {
    float e = __expf(2.f * x);
    return (e - 1.f) * __builtin_amdgcn_rcpf(e + 1.f);
}
__device__ __forceinline__ float atanh_fast(float x) {
    return 0.5f * __logf((1.f + x) * __builtin_amdgcn_rcpf(1.f - x));
}

// fragment index for A-side buffers: element (row, uint-col c)
__device__ __forceinline__ size_t fragidx(int row, int c) {
    return ((size_t)((row >> 4) * 4 + (c >> 4)) << 8) + ((((c >> 2) & 3) * 16 + (row & 15)) << 2) + (c & 3);
}

// ---------------- pass B: bin edges into 512-node buckets ----------------
__global__ __launch_bounds__(256) void k_bucket(const int* __restrict__ src, const int* __restrict__ dst,
                                                const float* __restrict__ ew, int* __restrict__ gcur,
                                                int2* __restrict__ staging, int E, int NBUCK) {
    __shared__ int hist[512];
    const int tid = threadIdx.x;
    const int e0 = blockIdx.x * PBE;
    for (int i = tid; i < 512; i += 256) hist[i] = 0;
    __syncthreads();
    #pragma unroll 4
    for (int j = 0; j < PBE / 256; j++) {
        int e = e0 + j * 256 + tid;
        if (e < E) atomicAdd(&hist[dst[e] >> NBH], 1);
    }
    __syncthreads();
    for (int b = tid; b < NBUCK; b += 256) {
        int c = hist[b];
        hist[b] = c ? atomicAdd(&gcur[b], c) : 0;
    }
    __syncthreads();
    #pragma unroll 4
    for (int j = 0; j < PBE / 256; j++) {
        int e = e0 + j * 256 + tid;
        if (e < E) {
            int d = dst[e];
            int bkt = d >> NBH;
            int pos = atomicAdd(&hist[bkt], 1);
            if (pos < BCAP)
                staging[(size_t)bkt * BCAP + pos] =
                    make_int2((src[e] & 0x1FFFF) | ((d & (BNODES - 1)) << 17), __float_as_int(ew[e]));
        }
    }
}

// ---------------- pass C: per-bucket CSR build ----------------
// Final csr.x holds PRESCALED src offset (src*64 uints) for the aggregation gather.
__global__ __launch_bounds__(256) void k_cbuild(const int* __restrict__ gcur, const int2* __restrict__ staging,
                                                int2* __restrict__ csr, int2* __restrict__ rp2, int N) {
    __shared__ int cnt[BNODES];
    __shared__ int base[BNODES];
    __shared__ int sbuf[256];
    const int tid = threadIdx.x;
    const int b = blockIdx.x;
    const int bcnt = min(gcur[b], BCAP);
    const int wbase = b * BWIN;
    const int2* st = staging + (size_t)b * BCAP;

    for (int i = tid; i < BNODES; i += 256) cnt[i] = 0;
    __syncthreads();
    for (int i = tid; i < bcnt; i += 256) {
        int nl = (st[i].x >> 17) & (BNODES - 1);
        atomicAdd(&cnt[nl], 1);
    }
    __syncthreads();
    int p0 = (cnt[2 * tid] + 3) & ~3;
    int p1 = (cnt[2 * tid + 1] + 3) & ~3;
    int s = p0 + p1;
    sbuf[tid] = s;
    __syncthreads();
    for (int off = 1; off < 256; off <<= 1) {
        int add = (tid >= off) ? sbuf[tid - off] : 0;
        __syncthreads();
        sbuf[tid] += add;
        __syncthreads();
    }
    int excl = sbuf[tid] - s;
    base[2 * tid] = excl;
    base[2 * tid + 1] = excl + p0;
    __syncthreads();
    for (int i = tid; i < BNODES; i += 256) {
        int node = b * BNODES + i;
        int c = cnt[i];
        int pd = (c + 3) & ~3;
        int gb = wbase + base[i];
        if (node < N) rp2[node] = make_int2(gb, pd);
        for (int k = c; k < pd; k++) csr[gb + k] = make_int2(0, 0);
    }
    __syncthreads();
    for (int i = tid; i < BNODES; i += 256) cnt[i] = wbase + base[i];
    __syncthreads();
    for (int i = tid; i < bcnt; i += 256) {
        int2 p = st[i];
        int nl = (p.x >> 17) & (BNODES - 1);
        int pos = atomicAdd(&cnt[nl], 1);
        csr[pos] = make_int2((p.x & 0x1FFFF) << 6, p.y);   // prescaled: src*64
    }
}

// ---------------- prep: split W into fragment-ordered bf16 hi/lo ----------------
__global__ __launch_bounds__(256) void k_wprep(const float* __restrict__ W1, const float* __restrict__ W2,
                                               unsigned* __restrict__ WH1, unsigned* __restrict__ WL1,
                                               unsigned* __restrict__ WH2, unsigned* __restrict__ WL2) {
    int f = (blockIdx.x & 31) * 256 + threadIdx.x;   // [0, 8192)
    const float* W = (blockIdx.x < 32) ? W1 : W2;
    unsigned* WH = (blockIdx.x < 32) ? WH1 : WH2;
    unsigned* WL = (blockIdx.x < 32) ? WL1 : WL2;
    int frag = f >> 8, rem = f & 255;
    int lane = rem >> 2, j = rem & 3;
    int lr = lane & 15, lg = lane >> 4;
    int wid = frag >> 3, ct = (frag >> 2) & 1, kt = frag & 3;
    int n = wid * 32 + 2 * lr + ct;
    int c = kt * 16 + lg * 4 + j;
    float a = W[n * 128 + 2 * c], b = W[n * 128 + 2 * c + 1];
    short ha, la, hb, lb;
    splitf(a, ha, la); splitf(b, hb, lb);
    WH[f] = packsplit_hi(ha, hb);
    WL[f] = packsplit_hi(la, lb);
}

// ---------------- prep: hyperbolic bias vectors ----------------
__global__ __launch_bounds__(64) void k_bias(const float* __restrict__ B1, const float* __restrict__ B2,
                                             float2* __restrict__ HB) {
    const int lane = threadIdx.x;
    const float* B = (blockIdx.x == 0) ? B1 : B2;
    float2 bb = *(const float2*)(B + 2 * lane);
    float nb2 = wsum(bb.x * bb.x + bb.y * bb.y);
    float nb = fmaxf(sqrtf(nb2), MINN);
    float tbc = fminf(tanh_fast(nb), MAXN);
    float fb = tbc / nb;
    HB[blockIdx.x * 65 + lane] = make_float2(fb * bb.x, fb * bb.y);
    if (lane == 0) HB[blockIdx.x * 65 + 64] = make_float2(tbc * tbc, 0.f);
}

// ---------------- prep: split x into fragment-ordered bf16 hi/lo + norms ----------------
__global__ __launch_bounds__(256) void k_encode(const float* __restrict__ X,
                                                unsigned* __restrict__ XH, unsigned* __restrict__ XL,
                                                float2* __restrict__ NRM, int N) {
    const int lane = threadIdx.x & 63;
    const int wid = threadIdx.x >> 6;
    int row = blockIdx.x * 4 + wid;
    if (row >= N) return;
    float2 u = *(const float2*)(X + (size_t)row * 128 + 2 * lane);
    float n2 = wsum(u.x * u.x + u.y * u.y);
    short h0, l0, h1, l1;
    splitf(u.x, h0, l0); splitf(u.y, h1, l1);
    size_t idx = fragidx(row, lane);
    XH[idx] = packsplit_hi(h0, h1);
    XL[idx] = packsplit_hi(l0, l1);
    if (lane == 0) {
        float n0 = fmaxf(sqrtf(n2), MINN);
        NRM[row] = make_float2(n0, fminf(n0, ATMAX));
    }
}

// ---------------- fused HypLinear: fragment loads + direct-store epilogue (round-16 form) ----------------
// Wave owns cols [wid*32, wid*32+32); tile ct covers interleaved cols wid*32+2*lr+ct,
// so a lane's (acc0[r], acc1[r]) is the adjacent pair (2c, 2c+1) -> direct f16 pack+store.
__global__ __launch_bounds__(256) void k_linear(
    const unsigned* __restrict__ XHf, const unsigned* __restrict__ XLf,
    const unsigned* __restrict__ WHf, const unsigned* __restrict__ WLf,
    const float2* __restrict__ HB, const float2* __restrict__ NRM,
    unsigned* __restrict__ OUT, int N)
{
    __shared__ float pmn[4][16][4];
    __shared__ float pdm[4][16][4];

    const int lane = threadIdx.x & 63;
    const int wid = threadIdx.x >> 6;
    const int lr = lane & 15;
    const int lg = lane >> 4;
    const int tbase = blockIdx.x * 4;

    // B fragments: contiguous 1KB loads
    short8 Bh[2][4], Bl[2][4];
    #pragma unroll
    for (int ct = 0; ct < 2; ct++) {
        #pragma unroll
        for (int kt = 0; kt < 4; kt++) {
            const int fb = ((wid * 2 + ct) * 4 + kt) << 8;
            Bh[ct][kt] = *(const short8*)(WHf + fb + lane * 4);
            Bl[ct][kt] = *(const short8*)(WLf + fb + lane * 4);
        }
    }
    const float2 hbc = HB[wid * 16 + lr];   // hb elems (2c, 2c+1) for c = wid*16+lr
    const float y2 = HB[64].x;

    f32x4 acc[4][2];

    #pragma unroll
    for (int t = 0; t < 4; t++) {
        const int row0 = (tbase + t) << 4;
        if (row0 >= N) break;

        short8 Ah[4], Al[4];
        #pragma unroll
        for (int kt = 0; kt < 4; kt++) {
            const int fa = ((tbase + t) * 4 + kt) << 8;
            Ah[kt] = *(const short8*)(XHf + fa + lane * 4);
            Al[kt] = *(const short8*)(XLf + fa + lane * 4);
        }

        f32x4 a0 = {0.f, 0.f, 0.f, 0.f}, a1 = {0.f, 0.f, 0.f, 0.f};
        #pragma unroll
        for (int kt = 0; kt < 4; kt++) {
            a0 = __builtin_amdgcn_mfma_f32_16x16x32_bf16(Ah[kt], Bh[0][kt], a0, 0, 0, 0);
            a1 = __builtin_amdgcn_mfma_f32_16x16x32_bf16(Ah[kt], Bh[1][kt], a1, 0, 0, 0);
            a0 = __builtin_amdgcn_mfma_f32_16x16x32_bf16(Al[kt], Bh[0][kt], a0, 0, 0, 0);
            a1 = __builtin_amdgcn_mfma_f32_16x16x32_bf16(Al[kt], Bh[1][kt], a1, 0, 0, 0);
            a0 = __builtin_amdgcn_mfma_f32_16x16x32_bf16(Ah[kt], Bl[0][kt], a0, 0, 0, 0);
            a1 = __builtin_amdgcn_mfma_f32_16x16x32_bf16(Ah[kt], Bl[1][kt], a1, 0, 0, 0);
        }
        acc[t][0] = a0; acc[t][1] = a1;

        // per-row partials over this wave's 32 cols; C row = lg*4 + r
        float pm[4], pd[4];
        #pragma unroll
        for (int r = 0; r < 4; r++) {
            pm[r] = a0[r] * a0[r] + a1[r] * a1[r];
            pd[r] = a0[r] * hbc.x + a1[r] * hbc.y;
        }
        #pragma unroll
        for (int s = 1; s <= 8; s <<= 1) {
            #pragma unroll
            for (int r = 0; r < 4; r++) {
                pm[r] += __shfl_xor(pm[r], s, 64);
                pd[r] += __shfl_xor(pd[r], s, 64);
            }
        }
        if (lr == 0) {
            #pragma unroll
            for (int r = 0; r < 4; r++) {
                pmn[t][lg * 4 + r][wid] = pm[r];
                pdm[t][lg * 4 + r][wid] = pd[r];
            }
        }
    }
    __syncthreads();

    #pragma unroll
    for (int t = 0; t < 4; t++) {
        const int row0 = (tbase + t) << 4;
        if (row0 >= N) break;

        // chain for row row0+lr (computed redundantly by the 4 lg groups)
        float4 qm = *(const float4*)pmn[t][lr];
        float4 qd = *(const float4*)pdm[t][lr];
        float mn2 = (qm.x + qm.y) + (qm.z + qm.w);
        float dmb = (qd.x + qd.y) + (qd.z + qd.w);
        const int crow = row0 + lr;
        float caf1 = 0.f, cbs = 0.f;
        if (crow < N) {
            float2 nr = NRM[crow];
            float xn = fmaxf(nr.x, MINN);
            float axn = nr.y;
            float mxn = fmaxf(sqrtf(mn2), MINN);
            float arg = (mxn / xn) * axn;
            float thc = fminf(tanh_fast(arg), MAXN);
            float f1 = thc / mxn;
            float x2 = thc * thc;
            float xy = f1 * dmb;
            float ca = 1.f + 2.f * xy + y2;
            float cb = 1.f - x2;
            float inv = 1.f / fmaxf(1.f + 2.f * xy + x2 * y2, MINN);
            float ng2 = inv * inv * (ca * ca * x2 + 2.f * ca * cb * xy + cb * cb * y2);
            float ng = fmaxf(sqrtf(ng2), MINN);
            float lf = atanh_fast(fminf(ng, MAXN)) / ng;
            float sle = lf * inv;
            caf1 = sle * ca * f1;
            cbs = sle * cb;
        }
        #pragma unroll
        for (int r = 0; r < 4; r++) {
            const int q = lg * 4 + r;
            float c1 = __shfl(caf1, q, 16);
            float c2 = __shfl(cbs, q, 16);
            const int row = row0 + q;
            if (row < N) {
                float o0 = c1 * acc[t][0][r] + c2 * hbc.x;
                float o1 = c1 * acc[t][1][r] + c2 * hbc.y;
                OUT[(size_t)row * 64 + wid * 16 + lr] = pack_f16_rn(o0, o1);
            }
        }
    }
}

// ---------------- fused aggregation + HypAct ----------------
// XT is f16-packed; csr.x prescaled (src*64). Unpack+FMA fused via v_fma_mix_f32.
__global__ __launch_bounds__(256) void k_aggact(const unsigned* __restrict__ XT, const int2* __restrict__ rp2,
                                                const int2* __restrict__ csr,
                                                float* __restrict__ OUTF,
                                                unsigned* __restrict__ OUTH, unsigned* __restrict__ OUTL,
                                                float2* __restrict__ NRM, int N, int last) {
    const int lane = threadIdx.x & 63;
    const int wid = threadIdx.x >> 6;
    int node = blockIdx.x * 4 + wid;
    if (node >= N) return;
    int2 rr = rp2[node];
    int b = __builtin_amdgcn_readfirstlane(rr.x);
    int cnt = __builtin_amdgcn_readfirstlane(rr.y);
    int e8 = b + (cnt & ~7);

    float ax[8], ay[8];
    #pragma unroll
    for (int j = 0; j < 8; j++) { ax[j] = 0.f; ay[j] = 0.f; }

    for (int i = b; i < e8; i += 8) {
        int2 c[8];
        #pragma unroll
        for (int j = 0; j < 8; j++) c[j] = csr[i + j];
        unsigned v[8];
        #pragma unroll
        for (int j = 0; j < 8; j++) v[j] = XT[(unsigned)c[j].x + lane];
        #pragma unroll
        for (int j = 0; j < 8; j++)
            fma_mix2(ax[j], ay[j], v[j], __int_as_float(c[j].y));
    }
    if (cnt & 4) {
        int i = e8;
        int2 c[4];
        #pragma unroll
        for (int j = 0; j < 4; j++) c[j] = csr[i + j];
        unsigned v[4];
        #pragma unroll
        for (int j = 0; j < 4; j++) v[j] = XT[(unsigned)c[j].x + lane];
        #pragma unroll
        for (int j = 0; j < 4; j++)
            fma_mix2(ax[j], ay[j], v[j], __int_as_float(c[j].y));
    }
    float a0 = ((ax[0] + ax[1]) + (ax[2] + ax[3])) + ((ax[4] + ax[5]) + (ax[6] + ax[7]));
    float a1 = ((ay[0] + ay[1]) + (ay[2] + ay[3])) + ((ay[4] + ay[5]) + (ay[6] + ay[7]));

    // act: logmap0(proj(expmap0(agg))) = agg * min(n,ATMAX)/n
    float r0 = fmaxf(a0, 0.f), r1 = fmaxf(a1, 0.f);
    float n2 = a0 * a0 + a1 * a1;
    float q2 = r0 * r0 + r1 * r1;
    #pragma unroll
    for (int s = 32; s; s >>= 1) {
        n2 += __shfl_xor(n2, s, 64);
        q2 += __shfl_xor(q2, s, 64);
    }
    float n = fmaxf(sqrtf(n2), MINN);
    float cp = fminf(n, ATMAX) / n;
    float nq = fmaxf(cp * sqrtf(q2), MINN);
    float tq = fminf(tanh_fast(nq), MAXN);
    float f2 = tq / nq;
    float sc = f2 * cp;
    float o0 = sc * r0, o1 = sc * r1;
    if (last) {
        *(float2*)(OUTF + (size_t)node * 128 + 2 * lane) = make_float2(o0, o1);
    } else {
        short h0, l0, h1, l1;
        splitf(o0, h0, l0); splitf(o1, h1, l1);
        size_t idx = fragidx(node, lane);
        OUTH[idx] = packsplit_hi(h0, h1);
        OUTL[idx] = packsplit_hi(l0, l1);
        if (lane == 0) NRM[node] = make_float2(tq, fminf(nq, ATMAX));
    }
}

extern "C" void kernel_launch(void* const* d_in, const int* in_sizes, int n_in,
                              void* d_out, int out_size, void* d_ws, size_t ws_size,
                              hipStream_t stream) {
    const float* x  = (const float*)d_in[0];
    const float* W1 = (const float*)d_in[1];
    const float* b1 = (const float*)d_in[2];
    const float* W2 = (const float*)d_in[3];
    const float* b2 = (const float*)d_in[4];
    const float* ew = (const float*)d_in[5];
    const int* src  = (const int*)d_in[6];
    const int* dst  = (const int*)d_in[7];
    const int N = in_sizes[0] / 128;
    const int E = in_sizes[5];
    float* out = (float*)d_out;

    const int NBUCK = (N + BNODES - 1) >> NBH;
    const int EB = (E + PBE - 1) / PBE;
    const int ntiles = (N + 15) / 16;

    char* w = (char*)d_ws;
    unsigned* xt  = (unsigned*)w; w += (size_t)N * 64 * 4;          // f16 tangent (linear->agg), row-major
    unsigned* xhf = (unsigned*)w; w += (size_t)ntiles * 1024 * 4;   // fragment-ordered hi
    unsigned* xlf = (unsigned*)w; w += (size_t)ntiles * 1024 * 4;   // fragment-ordered lo
    int2*   csr   = (int2*)w;   w += (size_t)NBUCK * BWIN * 8;
    float2* nrm   = (float2*)w; w += (size_t)N * 8;
    int2*   rp2   = (int2*)w;   w += (size_t)N * 8;
    int2*   staging = (int2*)w; w += (size_t)NBUCK * BCAP * 8;
    unsigned* wh1 = (unsigned*)w; w += 8192 * 4;
    unsigned* wl1 = (unsigned*)w; w += 8192 * 4;
    unsigned* wh2 = (unsigned*)w; w += 8192 * 4;
    unsigned* wl2 = (unsigned*)w; w += 8192 * 4;
    float2* hbuf  = (float2*)w; w += 2 * 65 * 8;
    int*    gcur  = (int*)w;    w += (size_t)NBUCK * 4 + 256;

    hipMemsetAsync(gcur, 0, (size_t)NBUCK * 4, stream);
    k_bucket<<<EB, 256, 0, stream>>>(src, dst, ew, gcur, staging, E, NBUCK);
    k_cbuild<<<NBUCK, 256, 0, stream>>>(gcur, staging, csr, rp2, N);
    k_wprep<<<64, 256, 0, stream>>>(W1, W2, wh1, wl1, wh2, wl2);
    k_bias<<<2, 64, 0, stream>>>(b1, b2, hbuf);

    const int rowblocks = (N + 3) / 4;
    const int nlb = (ntiles + 3) / 4;

    // encode: f32 x -> fragment-ordered hi/lo + norms
    k_encode<<<rowblocks, 256, 0, stream>>>(x, xhf, xlf, nrm, N);
    // layer 1
    k_linear<<<nlb, 256, 0, stream>>>(xhf, xlf, wh1, wl1, hbuf, nrm, xt, N);
    k_aggact<<<rowblocks, 256, 0, stream>>>(xt, rp2, csr, nullptr, xhf, xlf, nrm, N, 0);
    // layer 2 (fragment inputs + norms from aggact)
    k_linear<<<nlb, 256, 0, stream>>>(xhf, xlf, wh2, wl2, hbuf + 65, nrm, xt, N);
    k_aggact<<<rowblocks, 256, 0, stream>>>(xt, rp2, csr, out, nullptr, nullptr, nullptr, N, 1);
}